// Round 5
// baseline (193.200 us; speedup 1.0000x reference)
//
#include <hip/hip_runtime.h>

// Problem constants
#define NHEADS   8
#define EMB_     128
#define BT_      512        // b*t = 4*128
#define HIN_     1024
#define NQ_      4096       // BT_*NHEADS
#define NKEY_    50000
#define NGRP_REAL_ 3125     // 3125*16 = 50000 exactly: groups >= 3125 are pure pad
#define NGRP_    3200       // padded groups of 16 (64 slices * 50)
#define NPAIR_   1600       // 2-group pairs
#define NPADKEYS_ 1200.0f   // zero pad keys each add exp2(0)=1 to lsum: exact
#define GPS_     50         // groups per slice (even: preserves ping-pong pairing)
#define NSLICES_ 64         // 16x64 = 1024 blocks = exactly 4 blocks/CU

#define PROJB_   512        // proj tiles 2048, 4 waves/block
#define CONVB_   1024       // convert blocks (grid-stride over 3200 groups)

// scale = 128^-0.25 (reference) * log2(e) (scores land directly in exp2 domain)
#define QSCALE   (0.29730177875068026f * 1.4426950408889634f)

typedef __attribute__((ext_vector_type(8))) short short8v;   // 8 bf16 = 4 VGPRs
typedef __attribute__((ext_vector_type(4))) float float4v;   // MFMA C/D frag

#if __has_builtin(__builtin_amdgcn_exp2f)
#define EXP2F(x) __builtin_amdgcn_exp2f(x)
#else
#define EXP2F(x) exp2f(x)
#endif

__device__ __forceinline__ short f2bf(float f) {  // fp32 -> bf16 bits, RNE
  unsigned u = __float_as_uint(f);
  u += 0x7fffu + ((u >> 16) & 1u);
  return (short)(u >> 16);
}
__device__ __forceinline__ float bf2f(short h) {
  return __uint_as_float(((unsigned)(unsigned short)h) << 16);
}

// v_cvt_pk_bf16_f32: S0 -> low half, S1 -> high half (m240: no builtin; T12 asm)
#if __has_builtin(__builtin_amdgcn_cvt_pk_bf16_f32)
typedef __attribute__((ext_vector_type(2))) __bf16 bf16x2;
__device__ __forceinline__ unsigned pk2(float a, float b) {
  bf16x2 r = __builtin_amdgcn_cvt_pk_bf16_f32(a, b);
  union { bf16x2 v; unsigned u; } c; c.v = r; return c.u;
}
#else
__device__ __forceinline__ unsigned pk2(float a, float b) {
  unsigned r;
  asm("v_cvt_pk_bf16_f32 %0, %1, %2" : "=v"(r) : "v"(a), "v"(b));
  return r;
}
#endif

// ---------------------------------------------------------------------------
// Kernel 0 (fused): proj + convert in one dispatch.
// Convert: keys fp32 -> bf16 fragment-order (dense 16 B/lane stores), plus
// per-pair V-fragment table vfr[pg][Q][{hi,lo}][8 bf16] feeding the PV
// MFMA in attn (A-operand rows: 0 = v_hi, 1 = ones, 2 = v_lo, rest 0).
// Slot order per (pg,Q): [vE(Q*4..+3), vO(Q*4..+3)] matching the PV k-slots.
// Proj: q = (x @ Wq^T) * QSCALE -> bf16 (r9 structure, unchanged).
// ---------------------------------------------------------------------------
__global__ __launch_bounds__(256) void prep_kernel(
    const float* __restrict__ x, const float* __restrict__ Wq,
    short* __restrict__ qb,
    const float* __restrict__ keys, const float* __restrict__ values,
    short* __restrict__ keys_fr, short* __restrict__ vfr) {
  if (blockIdx.x < PROJB_) {
    // ---------------- proj ----------------
    const int wave = threadIdx.x >> 6, lane = threadIdx.x & 63;
    const int quad = lane >> 4, ln = lane & 15;
    const int tile = blockIdx.x * 4 + wave;        // 2048 tiles
    const int mt = tile >> 6, ot = tile & 63;      // 32 m-tiles x 64 o-tiles
    const float* xrow = x  + (mt * 16 + ln) * HIN_ + quad * 8;
    const float* wrow = Wq + (ot * 16 + ln) * HIN_ + quad * 8;
    float4v d = {0.f, 0.f, 0.f, 0.f};

    float4 xa0 = *(const float4*)(xrow);
    float4 xa1 = *(const float4*)(xrow + 4);
    float4 wa0 = *(const float4*)(wrow);
    float4 wa1 = *(const float4*)(wrow + 4);
    float4 xb0 = *(const float4*)(xrow + 32);
    float4 xb1 = *(const float4*)(xrow + 36);
    float4 wb0 = *(const float4*)(wrow + 32);
    float4 wb1 = *(const float4*)(wrow + 36);

#pragma unroll 1
    for (int k0 = 0; k0 < HIN_; k0 += 64) {
      union { short8v s8; unsigned u[4]; } af, bf;
      af.u[0] = pk2(xa0.x, xa0.y); af.u[1] = pk2(xa0.z, xa0.w);
      af.u[2] = pk2(xa1.x, xa1.y); af.u[3] = pk2(xa1.z, xa1.w);
      bf.u[0] = pk2(wa0.x, wa0.y); bf.u[1] = pk2(wa0.z, wa0.w);
      bf.u[2] = pk2(wa1.x, wa1.y); bf.u[3] = pk2(wa1.z, wa1.w);
      if (k0 + 64 < HIN_) {
        xa0 = *(const float4*)(xrow + k0 + 64);
        xa1 = *(const float4*)(xrow + k0 + 68);
        wa0 = *(const float4*)(wrow + k0 + 64);
        wa1 = *(const float4*)(wrow + k0 + 68);
      }
      d = __builtin_amdgcn_mfma_f32_16x16x32_bf16(af.s8, bf.s8, d, 0, 0, 0);

      af.u[0] = pk2(xb0.x, xb0.y); af.u[1] = pk2(xb0.z, xb0.w);
      af.u[2] = pk2(xb1.x, xb1.y); af.u[3] = pk2(xb1.z, xb1.w);
      bf.u[0] = pk2(wb0.x, wb0.y); bf.u[1] = pk2(wb0.z, wb0.w);
      bf.u[2] = pk2(wb1.x, wb1.y); bf.u[3] = pk2(wb1.z, wb1.w);
      if (k0 + 96 < HIN_) {
        xb0 = *(const float4*)(xrow + k0 + 96);
        xb1 = *(const float4*)(xrow + k0 + 100);
        wb0 = *(const float4*)(wrow + k0 + 96);
        wb1 = *(const float4*)(wrow + k0 + 100);
      }
      d = __builtin_amdgcn_mfma_f32_16x16x32_bf16(af.s8, bf.s8, d, 0, 0, 0);
    }
#pragma unroll
    for (int r2 = 0; r2 < 4; ++r2)
      qb[(mt * 16 + quad * 4 + r2) * HIN_ + ot * 16 + ln] = f2bf(d[r2] * QSCALE);
  } else {
    // ---------------- convert ----------------
    const int cb = blockIdx.x - PROJB_;
    const int t  = threadIdx.x;
#pragma unroll 1
    for (int g = cb; g < NGRP_; g += CONVB_) {
      if (g < NGRP_REAL_) {
        // source: 32 B contiguous; key row g*16 + (t&15), cols (t>>4)*8..+7
        const float* src = keys + (g * 16 + (t & 15)) * EMB_ + (t >> 4) * 8;
        float4 v0 = ((const float4*)src)[0];
        float4 v1 = ((const float4*)src)[1];
        union { short8v s8; unsigned u[4]; } o;
        o.u[0] = pk2(v0.x, v0.y); o.u[1] = pk2(v0.z, v0.w);
        o.u[2] = pk2(v1.x, v1.y); o.u[3] = pk2(v1.z, v1.w);
        ((short8v*)keys_fr)[g * 256 + t] = o.s8;   // dense 16 B/lane
      } else {
        short8v z = (short8v)0;                    // pad groups -> score 0
        ((short8v*)keys_fr)[g * 256 + t] = z;
      }
    }
    // ---- V-fragment table: 6400 work items (pg 0..1599, Q 0..3) ----
    const int wi = cb * 256 + t;
    if (wi < NPAIR_ * 4) {
      const int pg = wi >> 2, Q = wi & 3;
      short hi[8], lo[8];
#pragma unroll
      for (int e = 0; e < 4; ++e) {
        int idxE = pg * 32 + Q * 4 + e;            // even group 2*pg
        int idxO = idxE + 16;                      // odd group 2*pg+1
        float fE = (idxE < NKEY_) ? values[idxE] : 0.f;
        float fO = (idxO < NKEY_) ? values[idxO] : 0.f;
        hi[e]     = f2bf(fE); lo[e]     = f2bf(fE - bf2f(hi[e]));
        hi[4 + e] = f2bf(fO); lo[4 + e] = f2bf(fO - bf2f(hi[4 + e]));
      }
      short* dst = vfr + pg * 64 + Q * 16;         // [pg][Q][2][8 shorts]
#pragma unroll
      for (int e = 0; e < 8; ++e) { dst[e] = hi[e]; dst[8 + e] = lo[e]; }
    }
  }
}

// ---------------------------------------------------------------------------
// Kernel 1: flash-decoding attention. r3 restructure, r4 tweak: NO forced
// min-waves in launch_bounds (r3's (256,4) forced a 128-VGPR cap; live set
// ~140 -> would spill in the hot loop; let the allocator pick instead).
// Scores via SWAPPED mfma(K,Q): each lane owns a q-COLUMN with keys on the
// register axis = exactly the B-fragment layout for a second MFMA
// D = Vrows x P (A row0 = v_hi, row1 = ones, row2 = v_lo). That one MFMA per
// sub per 2 groups replaces 64 VALU fma/add (the measured 44% VALUBusy long
// pole) AND the entire epilogue shuffle reduce -- lsum/asum land pre-reduced
// in quad-0 lanes. Keeps: depth-2 key ping-pong, setprio on score clusters,
// XCD-chunked 1024-block grid (r2: FETCH 51.9->10.6 MB).
// ---------------------------------------------------------------------------
__global__ __launch_bounds__(256) void attn_kernel(
    const short* __restrict__ qb,        // bf16 [NQ_][128]
    const short* __restrict__ keys_fr,   // bf16, fragment order
    const short* __restrict__ vfr,       // bf16 V-fragments [1600][4][2][8]
    float* __restrict__ partials) {      // [NQ_][NSLICES_][2] = {l, acc}
  const int t     = threadIdx.x;
  const int wave  = t >> 6;
  const int lane  = t & 63;
  const int quad  = lane >> 4;
  const int ln    = lane & 15;
  const int l     = blockIdx.x;                  // 0..1023
  const int xcd   = l & 7;                       // assumed hw XCD = id%8
  const int j     = l >> 3;                      // 0..127 within XCD
  const int slice = xcd * 8 + (j >> 4);          // 8 slices per XCD
  const int chunk = j & 15;                      // q-chunk 0..15
  const int qbase = chunk * 256 + wave * 64;
  const int g0    = slice * GPS_;
  const int g1    = g0 + GPS_;                   // all slices full (64*50)

  short8v a[4][4];                               // q fragments (B-operand now)
#pragma unroll
  for (int sub = 0; sub < 4; ++sub)
#pragma unroll
    for (int ks = 0; ks < 4; ++ks)
      a[sub][ks] = *(const short8v*)(qb + (qbase + sub * 16 + ln) * EMB_ + ks * 32 + quad * 8);

  float4v dpv[4];                                // PV accum: rows {vhi,1,vlo}
#pragma unroll
  for (int sub = 0; sub < 4; ++sub) dpv[sub] = (float4v){0.f, 0.f, 0.f, 0.f};

  // V-fragment addressing: data lanes (ln==0 hi, ln==2 lo) load from vfr;
  // ln==1 = ones constant, others zero.
  const bool datalane = (ln == 0) || (ln == 2);
  const unsigned cvf = (ln == 1) ? 0x3F803F80u : 0u;
  const unsigned vinv = datalane ? (unsigned)(quad * 16 + (ln == 2 ? 8 : 0)) : 0u;
  const unsigned dmask = datalane ? 0xFFFFFFFFu : 0u;

  short8v bA[4], bB[4];                          // key register ping-pong
#pragma unroll
  for (int ks = 0; ks < 4; ++ks)                 // preload group g0 / g0+1
    bA[ks] = *(const short8v*)(keys_fr + ((g0 * 4 + ks) * 64 + lane) * 8);
#pragma unroll
  for (int ks = 0; ks < 4; ++ks)
    bB[ks] = *(const short8v*)(keys_fr + (((g0 + 1) * 4 + ks) * 64 + lane) * 8);

#pragma unroll 1
  for (int g = g0; g < g1; g += 2) {
    // V-frag for this pair (consumed at iteration end: full latency cover)
    union { short8v s8; unsigned u[4]; } vfu, vlu;
    vlu.s8 = *(const short8v*)(vfr + (vinv + (((unsigned)((g >> 1) * 64)) & dmask)));
#pragma unroll
    for (int i = 0; i < 4; ++i) vfu.u[i] = datalane ? vlu.u[i] : cvf;

    // ---- even group: scores (swapped: keys=A rows, q=B cols) ----
    float4v dE[4], dO[4];
#pragma unroll
    for (int sub = 0; sub < 4; ++sub) dE[sub] = (float4v){0.f, 0.f, 0.f, 0.f};
    __builtin_amdgcn_s_setprio(1);
#pragma unroll
    for (int ks = 0; ks < 4; ++ks)
#pragma unroll
      for (int sub = 0; sub < 4; ++sub)
        dE[sub] = __builtin_amdgcn_mfma_f32_16x16x32_bf16(bA[ks], a[sub][ks], dE[sub], 0, 0, 0);
    __builtin_amdgcn_s_setprio(0);
    if (g + 2 < g1) {                            // refill while MFMAs run
#pragma unroll
      for (int ks = 0; ks < 4; ++ks)
        bA[ks] = *(const short8v*)(keys_fr + (((g + 2) * 4 + ks) * 64 + lane) * 8);
    }
#pragma unroll
    for (int sub = 0; sub < 4; ++sub)
#pragma unroll
      for (int r2 = 0; r2 < 4; ++r2) dE[sub][r2] = EXP2F(dE[sub][r2]);
    unsigned pbl[4][2];                          // even halves -> bf16, dE dies
#pragma unroll
    for (int sub = 0; sub < 4; ++sub) {
      pbl[sub][0] = pk2(dE[sub][0], dE[sub][1]);
      pbl[sub][1] = pk2(dE[sub][2], dE[sub][3]);
    }

    // ---- odd group ----
#pragma unroll
    for (int sub = 0; sub < 4; ++sub) dO[sub] = (float4v){0.f, 0.f, 0.f, 0.f};
    __builtin_amdgcn_s_setprio(1);
#pragma unroll
    for (int ks = 0; ks < 4; ++ks)
#pragma unroll
      for (int sub = 0; sub < 4; ++sub)
        dO[sub] = __builtin_amdgcn_mfma_f32_16x16x32_bf16(bB[ks], a[sub][ks], dO[sub], 0, 0, 0);
    __builtin_amdgcn_s_setprio(0);
    if (g + 3 < g1) {
#pragma unroll
      for (int ks = 0; ks < 4; ++ks)
        bB[ks] = *(const short8v*)(keys_fr + (((g + 3) * 4 + ks) * 64 + lane) * 8);
    }
#pragma unroll
    for (int sub = 0; sub < 4; ++sub)
#pragma unroll
      for (int r2 = 0; r2 < 4; ++r2) dO[sub][r2] = EXP2F(dO[sub][r2]);

    // ---- PV + lsum via MFMA: dpv += Vrows x P (k = 32 keys of the pair) ----
#pragma unroll
    for (int sub = 0; sub < 4; ++sub) {
      union { short8v s8; unsigned u[4]; } pb;
      pb.u[0] = pbl[sub][0];
      pb.u[1] = pbl[sub][1];
      pb.u[2] = pk2(dO[sub][0], dO[sub][1]);
      pb.u[3] = pk2(dO[sub][2], dO[sub][3]);
      dpv[sub] = __builtin_amdgcn_mfma_f32_16x16x32_bf16(vfu.s8, pb.s8, dpv[sub], 0, 0, 0);
    }
  }

  // epilogue: quad 0 holds rows 0..3 = {p.vhi, lsum, p.vlo, 0}; col = q = ln
  if (quad == 0) {
#pragma unroll
    for (int sub = 0; sub < 4; ++sub) {
      int q = qbase + sub * 16 + ln;
      partials[(q * NSLICES_ + slice) * 2 + 0] = dpv[sub][1];
      partials[(q * NSLICES_ + slice) * 2 + 1] = dpv[sub][0] + dpv[sub][2];
    }
  }
}

// ---------------------------------------------------------------------------
// Kernel 2: combine slice partials, subtract exact pad-key lsum bias, mean
// over heads, add curiosity.
// ---------------------------------------------------------------------------
__global__ __launch_bounds__(256) void finalize_kernel(
    const float* __restrict__ partials, const float* __restrict__ cur,
    float* __restrict__ out) {
  int tid = blockIdx.x * 256 + threadIdx.x;      // 4096 threads
  int bt = tid >> 3, h = tid & 7;
  int q = bt * NHEADS + h;
  const float4* p = (const float4*)(partials + q * NSLICES_ * 2);
  float sl = 0.f, sa = 0.f;
#pragma unroll
  for (int i = 0; i < NSLICES_ / 2; ++i) {       // 2 slices per float4
    float4 v = p[i];
    sl += v.x + v.z;
    sa += v.y + v.w;
  }
  sl -= NPADKEYS_;                               // exact: pad keys give p=1,v=0
  float r = sa / sl;
  r += __shfl_xor(r, 1, 64);
  r += __shfl_xor(r, 2, 64);
  r += __shfl_xor(r, 4, 64);
  if (h == 0) out[bt] = r * (1.f / NHEADS) + cur[bt];
}

// ---------------------------------------------------------------------------
extern "C" void kernel_launch(void* const* d_in, const int* in_sizes, int n_in,
                              void* d_out, int out_size, void* d_ws, size_t ws_size,
                              hipStream_t stream) {
  (void)in_sizes; (void)n_in; (void)out_size; (void)ws_size;
  const float* x      = (const float*)d_in[0];   // (4,128,1024)
  const float* cur    = (const float*)d_in[1];   // (4,128)
  const float* Wq     = (const float*)d_in[2];   // (1024,1024)
  const float* keys   = (const float*)d_in[3];   // (50000,128)
  const float* values = (const float*)d_in[4];   // (50000,)
  float* out = (float*)d_out;                    // (4,128,1) fp32

  // workspace layout (16B-aligned), ~15.7 MiB total (same as r2)
  char* ws = (char*)d_ws;
  short* keys_fr = (short*)(ws);                        // 13,107,200 B (3200 grp)
  short* vfr     = (short*)(ws + 13107200);             //    204,800 B (V-frags)
  short* qb      = (short*)(ws + 13312000);             //  1,048,576 B
  float* part    = (float*)(ws + 14360576);             //  2,097,152 B (64 slices)

  hipLaunchKernelGGL(prep_kernel, dim3(PROJB_ + CONVB_), dim3(256), 0, stream,
                     x, Wq, qb, keys, values, keys_fr, vfr);
  hipLaunchKernelGGL(attn_kernel, dim3(1024), dim3(256), 0, stream,
                     qb, keys_fr, vfr, part);
  hipLaunchKernelGGL(finalize_kernel, dim3(16), dim3(256), 0, stream, part, cur, out);
}

// Round 6
// 181.314 us; speedup vs baseline: 1.0656x; 1.0656x over previous
//
#include <hip/hip_runtime.h>

// Problem constants
#define NHEADS   8
#define EMB_     128
#define BT_      512        // b*t = 4*128
#define HIN_     1024
#define NQ_      4096       // BT_*NHEADS
#define NKEY_    50000
#define NGRP_REAL_ 3125     // 3125*16 = 50000 exactly: groups >= 3125 are pure pad
#define NGRP_    3200       // padded groups of 16 (64 slices * 50)
#define NPADKEYS_ 1200.0f   // zero pad keys each add exp2(0)=1 to lsum: exact
#define GPS_     50         // groups per slice (even: preserves ping-pong pairing)
#define NSLICES_ 64         // 64 slices x 32 q-chunks = 2048 blocks

#define PROJB_   512        // proj tiles 2048, 4 waves/block
#define CONVB_   1024       // convert blocks (grid-stride over 3200 groups)

// scale = 128^-0.25 (reference) * log2(e) (scores land directly in exp2 domain)
#define QSCALE   (0.29730177875068026f * 1.4426950408889634f)

typedef __attribute__((ext_vector_type(8))) short short8v;   // 8 bf16 = 4 VGPRs
typedef __attribute__((ext_vector_type(4))) float float4v;   // MFMA C/D frag

#if __has_builtin(__builtin_amdgcn_exp2f)
#define EXP2F(x) __builtin_amdgcn_exp2f(x)
#else
#define EXP2F(x) exp2f(x)
#endif

__device__ __forceinline__ short f2bf(float f) {  // fp32 -> bf16 bits, RNE
  unsigned u = __float_as_uint(f);
  u += 0x7fffu + ((u >> 16) & 1u);
  return (short)(u >> 16);
}

#if __has_builtin(__builtin_amdgcn_cvt_pk_bf16_f32)
typedef __attribute__((ext_vector_type(2))) __bf16 bf16x2;
__device__ __forceinline__ unsigned pk2(float a, float b) {
  bf16x2 r = __builtin_amdgcn_cvt_pk_bf16_f32(a, b);
  union { bf16x2 v; unsigned u; } c; c.v = r; return c.u;
}
#else
__device__ __forceinline__ unsigned pk2(float a, float b) {
  unsigned r;
  asm("v_cvt_pk_bf16_f32 %0, %1, %2" : "=v"(r) : "v"(a), "v"(b));
  return r;
}
#endif

// ---------------------------------------------------------------------------
// Kernel 0 (fused): proj + convert in one dispatch (r2 version, reverted).
// Convert: output-centric dense stores (16 B/lane); source reads 32 B
// contiguous per lane. Groups 3125..3199 are pure zero-fill; their keys give
// score 0 -> p = exp2(0) = 1 with v = 0, corrected EXACTLY in finalize by
// subtracting NPADKEYS_ from lsum.
// Proj: q = (x @ Wq^T) * QSCALE -> bf16 (r9 structure).
// ---------------------------------------------------------------------------
__global__ __launch_bounds__(256) void prep_kernel(
    const float* __restrict__ x, const float* __restrict__ Wq,
    short* __restrict__ qb,
    const float* __restrict__ keys, const float* __restrict__ values,
    short* __restrict__ keys_fr, float* __restrict__ vpad) {
  if (blockIdx.x < PROJB_) {
    // ---------------- proj ----------------
    const int wave = threadIdx.x >> 6, lane = threadIdx.x & 63;
    const int quad = lane >> 4, ln = lane & 15;
    const int tile = blockIdx.x * 4 + wave;        // 2048 tiles
    const int mt = tile >> 6, ot = tile & 63;      // 32 m-tiles x 64 o-tiles
    const float* xrow = x  + (mt * 16 + ln) * HIN_ + quad * 8;
    const float* wrow = Wq + (ot * 16 + ln) * HIN_ + quad * 8;
    float4v d = {0.f, 0.f, 0.f, 0.f};

    float4 xa0 = *(const float4*)(xrow);
    float4 xa1 = *(const float4*)(xrow + 4);
    float4 wa0 = *(const float4*)(wrow);
    float4 wa1 = *(const float4*)(wrow + 4);
    float4 xb0 = *(const float4*)(xrow + 32);
    float4 xb1 = *(const float4*)(xrow + 36);
    float4 wb0 = *(const float4*)(wrow + 32);
    float4 wb1 = *(const float4*)(wrow + 36);

#pragma unroll 1
    for (int k0 = 0; k0 < HIN_; k0 += 64) {
      union { short8v s8; unsigned u[4]; } af, bf;
      af.u[0] = pk2(xa0.x, xa0.y); af.u[1] = pk2(xa0.z, xa0.w);
      af.u[2] = pk2(xa1.x, xa1.y); af.u[3] = pk2(xa1.z, xa1.w);
      bf.u[0] = pk2(wa0.x, wa0.y); bf.u[1] = pk2(wa0.z, wa0.w);
      bf.u[2] = pk2(wa1.x, wa1.y); bf.u[3] = pk2(wa1.z, wa1.w);
      if (k0 + 64 < HIN_) {
        xa0 = *(const float4*)(xrow + k0 + 64);
        xa1 = *(const float4*)(xrow + k0 + 68);
        wa0 = *(const float4*)(wrow + k0 + 64);
        wa1 = *(const float4*)(wrow + k0 + 68);
      }
      d = __builtin_amdgcn_mfma_f32_16x16x32_bf16(af.s8, bf.s8, d, 0, 0, 0);

      af.u[0] = pk2(xb0.x, xb0.y); af.u[1] = pk2(xb0.z, xb0.w);
      af.u[2] = pk2(xb1.x, xb1.y); af.u[3] = pk2(xb1.z, xb1.w);
      bf.u[0] = pk2(wb0.x, wb0.y); bf.u[1] = pk2(wb0.z, wb0.w);
      bf.u[2] = pk2(wb1.x, wb1.y); bf.u[3] = pk2(wb1.z, wb1.w);
      if (k0 + 96 < HIN_) {
        xb0 = *(const float4*)(xrow + k0 + 96);
        xb1 = *(const float4*)(xrow + k0 + 100);
        wb0 = *(const float4*)(wrow + k0 + 96);
        wb1 = *(const float4*)(wrow + k0 + 100);
      }
      d = __builtin_amdgcn_mfma_f32_16x16x32_bf16(af.s8, bf.s8, d, 0, 0, 0);
    }
#pragma unroll
    for (int r2 = 0; r2 < 4; ++r2)
      qb[(mt * 16 + quad * 4 + r2) * HIN_ + ot * 16 + ln] = f2bf(d[r2] * QSCALE);
  } else {
    // ---------------- convert ----------------
    const int cb = blockIdx.x - PROJB_;
    const int t  = threadIdx.x;
#pragma unroll 1
    for (int g = cb; g < NGRP_; g += CONVB_) {
      if (g < NGRP_REAL_) {
        // source: 32 B contiguous; key row g*16 + (t&15), cols (t>>4)*8..+7
        const float* src = keys + (g * 16 + (t & 15)) * EMB_ + (t >> 4) * 8;
        float4 v0 = ((const float4*)src)[0];
        float4 v1 = ((const float4*)src)[1];
        union { short8v s8; unsigned u[4]; } o;
        o.u[0] = pk2(v0.x, v0.y); o.u[1] = pk2(v0.z, v0.w);
        o.u[2] = pk2(v1.x, v1.y); o.u[3] = pk2(v1.z, v1.w);
        ((short8v*)keys_fr)[g * 256 + t] = o.s8;   // dense 16 B/lane
        if (t < 16) vpad[g * 16 + t] = values[g * 16 + t];
      } else {
        short8v z = (short8v)0;                    // pad groups -> score 0
        ((short8v*)keys_fr)[g * 256 + t] = z;
        if (t < 16) vpad[g * 16 + t] = 0.f;
      }
    }
  }
}

// ---------------------------------------------------------------------------
// Kernel 1: flash-decoding attention. r5 analysis: dur ~ 1/occupancy across
// r13/r15/r5 (occ 16.7/10.6/19.3 -> 72/122/87 us); kernel is latency-bound
// with both pipes <45% busy; residency is capped by UNIFIED VGPR+AGPR
// footprint (~160 live at sub=4), not by the grid. THIS ROUND: halve the
// per-wave q-tile (sub 4->2): a 64->32, lsum/asum 32->16, d 32->16 regs;
// grid 1024->2048 blocks (32 q-chunks x 64 slices). Merged even+odd MFMA
// cluster keeps 4 independent accumulator chains (r12). Hoisted zero-quad C
// removes the per-iter d-init movs. Keeps: r2 VALU accumulate (r3's PV-MFMA
// falsified: exp2 dominates VALU, restructure only added stalls), depth-2
// key ping-pong, setprio, XCD-chunked decode (FETCH 51.9->10.6 MB).
// ---------------------------------------------------------------------------
__global__ __launch_bounds__(256) void attn_kernel(
    const short* __restrict__ qb,        // bf16 [NQ_][128]
    const short* __restrict__ keys_fr,   // bf16, fragment order
    const float* __restrict__ vpad,      // [NGRP_*16]
    float* __restrict__ partials) {      // [NQ_][NSLICES_][2] = {l, acc}
  const int t     = threadIdx.x;
  const int wave  = t >> 6;
  const int lane  = t & 63;
  const int quad  = lane >> 4;
  const int ln    = lane & 15;
  const int l     = blockIdx.x;                  // 0..2047
  const int xcd   = l & 7;                       // assumed hw XCD = id%8
  const int j     = l >> 3;                      // 0..255 within XCD
  const int slice = xcd * 8 + (j >> 5);          // 8 slices per XCD
  const int chunk = j & 31;                      // q-chunk 0..31 (128 q each)
  const int qbase = chunk * 128 + wave * 32;
  const int g0    = slice * GPS_;
  const int g1    = g0 + GPS_;                   // all slices full (64*50)

  short8v a[2][4];                               // q fragments (32 VGPR)
#pragma unroll
  for (int sub = 0; sub < 2; ++sub)
#pragma unroll
    for (int ks = 0; ks < 4; ++ks)
      a[sub][ks] = *(const short8v*)(qb + (qbase + sub * 16 + ln) * EMB_ + ks * 32 + quad * 8);

  float lsum[2][4], asum[2][4];
#pragma unroll
  for (int i = 0; i < 2; ++i)
#pragma unroll
    for (int jj = 0; jj < 4; ++jj) { lsum[i][jj] = 0.f; asum[i][jj] = 0.f; }

  const float4v z4 = {0.f, 0.f, 0.f, 0.f};       // hoisted zero C operand

  short8v bA[4], bB[4];                          // key register ping-pong
  float vA, vB;
#pragma unroll
  for (int ks = 0; ks < 4; ++ks)                 // preload group g0 / g0+1
    bA[ks] = *(const short8v*)(keys_fr + ((g0 * 4 + ks) * 64 + lane) * 8);
  vA = vpad[g0 * 16 + ln];
#pragma unroll
  for (int ks = 0; ks < 4; ++ks)
    bB[ks] = *(const short8v*)(keys_fr + (((g0 + 1) * 4 + ks) * 64 + lane) * 8);
  vB = vpad[(g0 + 1) * 16 + ln];

#pragma unroll 1
  for (int g = g0; g < g1; g += 2) {
    // ---- merged even+odd score cluster: 16 MFMAs, 4 indep chains ----
    float4v dE[2], dO[2];
    __builtin_amdgcn_s_setprio(1);
    dE[0] = __builtin_amdgcn_mfma_f32_16x16x32_bf16(a[0][0], bA[0], z4, 0, 0, 0);
    dE[1] = __builtin_amdgcn_mfma_f32_16x16x32_bf16(a[1][0], bA[0], z4, 0, 0, 0);
    dO[0] = __builtin_amdgcn_mfma_f32_16x16x32_bf16(a[0][0], bB[0], z4, 0, 0, 0);
    dO[1] = __builtin_amdgcn_mfma_f32_16x16x32_bf16(a[1][0], bB[0], z4, 0, 0, 0);
#pragma unroll
    for (int ks = 1; ks < 4; ++ks) {
      dE[0] = __builtin_amdgcn_mfma_f32_16x16x32_bf16(a[0][ks], bA[ks], dE[0], 0, 0, 0);
      dE[1] = __builtin_amdgcn_mfma_f32_16x16x32_bf16(a[1][ks], bA[ks], dE[1], 0, 0, 0);
      dO[0] = __builtin_amdgcn_mfma_f32_16x16x32_bf16(a[0][ks], bB[ks], dO[0], 0, 0, 0);
      dO[1] = __builtin_amdgcn_mfma_f32_16x16x32_bf16(a[1][ks], bB[ks], dO[1], 0, 0, 0);
    }
    __builtin_amdgcn_s_setprio(0);

    // ---- refill key ping-pong + values while MFMAs run ----
    if (g + 2 < g1) {
#pragma unroll
      for (int ks = 0; ks < 4; ++ks)
        bA[ks] = *(const short8v*)(keys_fr + (((g + 2) * 4 + ks) * 64 + lane) * 8);
    }
    float vvA = vA;
    if (g + 2 < g1) vA = vpad[(g + 2) * 16 + ln];
    if (g + 3 < g1) {
#pragma unroll
      for (int ks = 0; ks < 4; ++ks)
        bB[ks] = *(const short8v*)(keys_fr + (((g + 3) * 4 + ks) * 64 + lane) * 8);
    }
    float vvB = vB;
    if (g + 3 < g1) vB = vpad[(g + 3) * 16 + ln];

    // ---- finish both groups: exp2 + lsum/asum accumulate ----
#pragma unroll
    for (int sub = 0; sub < 2; ++sub)
#pragma unroll
      for (int r2 = 0; r2 < 4; ++r2) {
        float pE = EXP2F(dE[sub][r2]);
        float pO = EXP2F(dO[sub][r2]);
        lsum[sub][r2] += pE + pO;
        asum[sub][r2] = fmaf(pE, vvA, asum[sub][r2]);
        asum[sub][r2] = fmaf(pO, vvB, asum[sub][r2]);
      }
  }

  // reduce over the 16 key-column lanes (same quad); lane ln==0 writes
#pragma unroll
  for (int sub = 0; sub < 2; ++sub)
#pragma unroll
    for (int r2 = 0; r2 < 4; ++r2) {
      float L = lsum[sub][r2], A = asum[sub][r2];
#pragma unroll
      for (int m = 1; m < 16; m <<= 1) {
        L += __shfl_xor(L, m, 64);
        A += __shfl_xor(A, m, 64);
      }
      if (ln == 0) {
        int q = qbase + sub * 16 + quad * 4 + r2;
        partials[(q * NSLICES_ + slice) * 2 + 0] = L;
        partials[(q * NSLICES_ + slice) * 2 + 1] = A;
      }
    }
}

// ---------------------------------------------------------------------------
// Kernel 2: combine slice partials, subtract exact pad-key lsum bias, mean
// over heads, add curiosity.
// ---------------------------------------------------------------------------
__global__ __launch_bounds__(256) void finalize_kernel(
    const float* __restrict__ partials, const float* __restrict__ cur,
    float* __restrict__ out) {
  int tid = blockIdx.x * 256 + threadIdx.x;      // 4096 threads
  int bt = tid >> 3, h = tid & 7;
  int q = bt * NHEADS + h;
  const float4* p = (const float4*)(partials + q * NSLICES_ * 2);
  float sl = 0.f, sa = 0.f;
#pragma unroll
  for (int i = 0; i < NSLICES_ / 2; ++i) {       // 2 slices per float4
    float4 v = p[i];
    sl += v.x + v.z;
    sa += v.y + v.w;
  }
  sl -= NPADKEYS_;                               // exact: pad keys give p=1,v=0
  float r = sa / sl;
  r += __shfl_xor(r, 1, 64);
  r += __shfl_xor(r, 2, 64);
  r += __shfl_xor(r, 4, 64);
  if (h == 0) out[bt] = r * (1.f / NHEADS) + cur[bt];
}

// ---------------------------------------------------------------------------
extern "C" void kernel_launch(void* const* d_in, const int* in_sizes, int n_in,
                              void* d_out, int out_size, void* d_ws, size_t ws_size,
                              hipStream_t stream) {
  (void)in_sizes; (void)n_in; (void)out_size; (void)ws_size;
  const float* x      = (const float*)d_in[0];   // (4,128,1024)
  const float* cur    = (const float*)d_in[1];   // (4,128)
  const float* Wq     = (const float*)d_in[2];   // (1024,1024)
  const float* keys   = (const float*)d_in[3];   // (50000,128)
  const float* values = (const float*)d_in[4];   // (50000,)
  float* out = (float*)d_out;                    // (4,128,1) fp32

  // workspace layout (16B-aligned), ~15.7 MiB total (same as r2)
  char* ws = (char*)d_ws;
  short* keys_fr = (short*)(ws);                        // 13,107,200 B (3200 grp)
  float* vpad    = (float*)(ws + 13107200);             //    204,800 B
  short* qb      = (short*)(ws + 13312000);             //  1,048,576 B
  float* part    = (float*)(ws + 14360576);             //  2,097,152 B (64 slices)

  hipLaunchKernelGGL(prep_kernel, dim3(PROJB_ + CONVB_), dim3(256), 0, stream,
                     x, Wq, qb, keys, values, keys_fr, vpad);
  hipLaunchKernelGGL(attn_kernel, dim3(2048), dim3(256), 0, stream,
                     qb, keys_fr, vpad, part);
  hipLaunchKernelGGL(finalize_kernel, dim3(16), dim3(256), 0, stream, part, cur, out);
}

// Round 7
// 174.604 us; speedup vs baseline: 1.1065x; 1.0384x over previous
//
#include <hip/hip_runtime.h>

// Problem constants
#define NHEADS   8
#define EMB_     128
#define BT_      512        // b*t = 4*128
#define HIN_     1024
#define NQ_      4096       // BT_*NHEADS
#define NKEY_    50000
#define NGRP_REAL_ 3125     // 3125*16 = 50000 exactly: groups >= 3125 are pure pad
#define NGRP_    3200       // padded groups of 16 (64 slices * 50)
#define NPADKEYS_ 1200.0f   // zero pad keys each add exp2(0)=1 to lsum: exact
#define GPS_     50         // groups per slice (even: preserves ping-pong pairing)
#define NSLICES_ 64         // 64 slices x 16 q-chunks = 1024 blocks = 4/CU

#define PROJB_   512        // proj tiles 2048, 4 waves/block
#define CONVB_   1024       // convert blocks (grid-stride over 3200 groups)

// scale = 128^-0.25 (reference) * log2(e) (scores land directly in exp2 domain)
#define QSCALE   (0.29730177875068026f * 1.4426950408889634f)

typedef __attribute__((ext_vector_type(8))) short short8v;   // 8 bf16 = 4 VGPRs
typedef __attribute__((ext_vector_type(4))) float float4v;   // MFMA C/D frag

#if __has_builtin(__builtin_amdgcn_exp2f)
#define EXP2F(x) __builtin_amdgcn_exp2f(x)
#else
#define EXP2F(x) exp2f(x)
#endif

__device__ __forceinline__ short f2bf(float f) {  // fp32 -> bf16 bits, RNE
  unsigned u = __float_as_uint(f);
  u += 0x7fffu + ((u >> 16) & 1u);
  return (short)(u >> 16);
}

#if __has_builtin(__builtin_amdgcn_cvt_pk_bf16_f32)
typedef __attribute__((ext_vector_type(2))) __bf16 bf16x2;
__device__ __forceinline__ unsigned pk2(float a, float b) {
  bf16x2 r = __builtin_amdgcn_cvt_pk_bf16_f32(a, b);
  union { bf16x2 v; unsigned u; } c; c.v = r; return c.u;
}
#else
__device__ __forceinline__ unsigned pk2(float a, float b) {
  unsigned r;
  asm("v_cvt_pk_bf16_f32 %0, %1, %2" : "=v"(r) : "v"(a), "v"(b));
  return r;
}
#endif

// ---------------------------------------------------------------------------
// Kernel 0 (fused): proj + convert in one dispatch (r2 version, unchanged).
// ---------------------------------------------------------------------------
__global__ __launch_bounds__(256) void prep_kernel(
    const float* __restrict__ x, const float* __restrict__ Wq,
    short* __restrict__ qb,
    const float* __restrict__ keys, const float* __restrict__ values,
    short* __restrict__ keys_fr, float* __restrict__ vpad) {
  if (blockIdx.x < PROJB_) {
    // ---------------- proj ----------------
    const int wave = threadIdx.x >> 6, lane = threadIdx.x & 63;
    const int quad = lane >> 4, ln = lane & 15;
    const int tile = blockIdx.x * 4 + wave;        // 2048 tiles
    const int mt = tile >> 6, ot = tile & 63;      // 32 m-tiles x 64 o-tiles
    const float* xrow = x  + (mt * 16 + ln) * HIN_ + quad * 8;
    const float* wrow = Wq + (ot * 16 + ln) * HIN_ + quad * 8;
    float4v d = {0.f, 0.f, 0.f, 0.f};

    float4 xa0 = *(const float4*)(xrow);
    float4 xa1 = *(const float4*)(xrow + 4);
    float4 wa0 = *(const float4*)(wrow);
    float4 wa1 = *(const float4*)(wrow + 4);
    float4 xb0 = *(const float4*)(xrow + 32);
    float4 xb1 = *(const float4*)(xrow + 36);
    float4 wb0 = *(const float4*)(wrow + 32);
    float4 wb1 = *(const float4*)(wrow + 36);

#pragma unroll 1
    for (int k0 = 0; k0 < HIN_; k0 += 64) {
      union { short8v s8; unsigned u[4]; } af, bf;
      af.u[0] = pk2(xa0.x, xa0.y); af.u[1] = pk2(xa0.z, xa0.w);
      af.u[2] = pk2(xa1.x, xa1.y); af.u[3] = pk2(xa1.z, xa1.w);
      bf.u[0] = pk2(wa0.x, wa0.y); bf.u[1] = pk2(wa0.z, wa0.w);
      bf.u[2] = pk2(wa1.x, wa1.y); bf.u[3] = pk2(wa1.z, wa1.w);
      if (k0 + 64 < HIN_) {
        xa0 = *(const float4*)(xrow + k0 + 64);
        xa1 = *(const float4*)(xrow + k0 + 68);
        wa0 = *(const float4*)(wrow + k0 + 64);
        wa1 = *(const float4*)(wrow + k0 + 68);
      }
      d = __builtin_amdgcn_mfma_f32_16x16x32_bf16(af.s8, bf.s8, d, 0, 0, 0);

      af.u[0] = pk2(xb0.x, xb0.y); af.u[1] = pk2(xb0.z, xb0.w);
      af.u[2] = pk2(xb1.x, xb1.y); af.u[3] = pk2(xb1.z, xb1.w);
      bf.u[0] = pk2(wb0.x, wb0.y); bf.u[1] = pk2(wb0.z, wb0.w);
      bf.u[2] = pk2(wb1.x, wb1.y); bf.u[3] = pk2(wb1.z, wb1.w);
      if (k0 + 96 < HIN_) {
        xb0 = *(const float4*)(xrow + k0 + 96);
        xb1 = *(const float4*)(xrow + k0 + 100);
        wb0 = *(const float4*)(wrow + k0 + 96);
        wb1 = *(const float4*)(wrow + k0 + 100);
      }
      d = __builtin_amdgcn_mfma_f32_16x16x32_bf16(af.s8, bf.s8, d, 0, 0, 0);
    }
#pragma unroll
    for (int r2 = 0; r2 < 4; ++r2)
      qb[(mt * 16 + quad * 4 + r2) * HIN_ + ot * 16 + ln] = f2bf(d[r2] * QSCALE);
  } else {
    // ---------------- convert ----------------
    const int cb = blockIdx.x - PROJB_;
    const int t  = threadIdx.x;
#pragma unroll 1
    for (int g = cb; g < NGRP_; g += CONVB_) {
      if (g < NGRP_REAL_) {
        // source: 32 B contiguous; key row g*16 + (t&15), cols (t>>4)*8..+7
        const float* src = keys + (g * 16 + (t & 15)) * EMB_ + (t >> 4) * 8;
        float4 v0 = ((const float4*)src)[0];
        float4 v1 = ((const float4*)src)[1];
        union { short8v s8; unsigned u[4]; } o;
        o.u[0] = pk2(v0.x, v0.y); o.u[1] = pk2(v0.z, v0.w);
        o.u[2] = pk2(v1.x, v1.y); o.u[3] = pk2(v1.z, v1.w);
        ((short8v*)keys_fr)[g * 256 + t] = o.s8;   // dense 16 B/lane
        if (t < 16) vpad[g * 16 + t] = values[g * 16 + t];
      } else {
        short8v z = (short8v)0;                    // pad groups -> score 0
        ((short8v*)keys_fr)[g * 256 + t] = z;
        if (t < 16) vpad[g * 16 + t] = 0.f;
      }
    }
  }
}

// ---------------------------------------------------------------------------
// Kernel 1: flash-decoding attention. Eliminations so far: not HBM-bound
// (r2: FETCH 52->10.6 MB, dur unchanged), not occupancy-bound (r6: occ
// 16.7->26.1%, dur WORSE), not VALU-throughput-bound (r3: fewer VALU ops,
// dur worse). r7 theory: per-wave PIPE-ALTERNATION -- program order
// [32 MFMA][~96 VALU] idles each pipe half the time and near-lockstep waves
// can't fill the gaps. Change: split the VALU block and interleave it
// BETWEEN the two MFMA clusters (even-MFMA -> exp2/accum(dE) -> odd-MFMA ->
// exp2/accum(dO)); dE dies before dO is born so VGPR stays ~108. Keeps: r2
// sub=4 / 1024-block XCD-chunked grid, depth-2 key ping-pong, setprio,
// hoisted zero-C (r6).
// ---------------------------------------------------------------------------
__global__ __launch_bounds__(256) void attn_kernel(
    const short* __restrict__ qb,        // bf16 [NQ_][128]
    const short* __restrict__ keys_fr,   // bf16, fragment order
    const float* __restrict__ vpad,      // [NGRP_*16]
    float* __restrict__ partials) {      // [NQ_][NSLICES_][2] = {l, acc}
  const int t     = threadIdx.x;
  const int wave  = t >> 6;
  const int lane  = t & 63;
  const int quad  = lane >> 4;
  const int ln    = lane & 15;
  const int l     = blockIdx.x;                  // 0..1023
  const int xcd   = l & 7;                       // assumed hw XCD = id%8
  const int j     = l >> 3;                      // 0..127 within XCD
  const int slice = xcd * 8 + (j >> 4);          // 8 slices per XCD
  const int chunk = j & 15;                      // q-chunk 0..15
  const int qbase = chunk * 256 + wave * 64;
  const int g0    = slice * GPS_;
  const int g1    = g0 + GPS_;                   // all slices full (64*50)

  short8v a[4][4];                               // q fragments
#pragma unroll
  for (int sub = 0; sub < 4; ++sub)
#pragma unroll
    for (int ks = 0; ks < 4; ++ks)
      a[sub][ks] = *(const short8v*)(qb + (qbase + sub * 16 + ln) * EMB_ + ks * 32 + quad * 8);

  float lsum[4][4], asum[4][4];
#pragma unroll
  for (int i = 0; i < 4; ++i)
#pragma unroll
    for (int jj = 0; jj < 4; ++jj) { lsum[i][jj] = 0.f; asum[i][jj] = 0.f; }

  const float4v z4 = {0.f, 0.f, 0.f, 0.f};       // hoisted zero C operand

  short8v bA[4], bB[4];                          // key register ping-pong
  float vA, vB;
#pragma unroll
  for (int ks = 0; ks < 4; ++ks)                 // preload group g0 / g0+1
    bA[ks] = *(const short8v*)(keys_fr + ((g0 * 4 + ks) * 64 + lane) * 8);
  vA = vpad[g0 * 16 + ln];
#pragma unroll
  for (int ks = 0; ks < 4; ++ks)
    bB[ks] = *(const short8v*)(keys_fr + (((g0 + 1) * 4 + ks) * 64 + lane) * 8);
  vB = vpad[(g0 + 1) * 16 + ln];

#pragma unroll 1
  for (int g = g0; g < g1; g += 2) {
    // ---- even cluster: 16 MFMAs on bA (4 indep chains) ----
    float4v dE[4];
    __builtin_amdgcn_s_setprio(1);
#pragma unroll
    for (int sub = 0; sub < 4; ++sub)
      dE[sub] = __builtin_amdgcn_mfma_f32_16x16x32_bf16(a[sub][0], bA[0], z4, 0, 0, 0);
#pragma unroll
    for (int ks = 1; ks < 4; ++ks)
#pragma unroll
      for (int sub = 0; sub < 4; ++sub)
        dE[sub] = __builtin_amdgcn_mfma_f32_16x16x32_bf16(a[sub][ks], bA[ks], dE[sub], 0, 0, 0);
    __builtin_amdgcn_s_setprio(0);
    if (g + 2 < g1) {                            // refill bA while MFMAs run
#pragma unroll
      for (int ks = 0; ks < 4; ++ks)
        bA[ks] = *(const short8v*)(keys_fr + (((g + 2) * 4 + ks) * 64 + lane) * 8);
    }
    float vvA = vA;
    if (g + 2 < g1) vA = vpad[(g + 2) * 16 + ln];

    // ---- VALU part A: finish even group (fills odd cluster's MFMA gap) ----
#pragma unroll
    for (int sub = 0; sub < 4; ++sub)
#pragma unroll
      for (int r2 = 0; r2 < 4; ++r2) {
        float pE = EXP2F(dE[sub][r2]);
        lsum[sub][r2] += pE;
        asum[sub][r2] = fmaf(pE, vvA, asum[sub][r2]);
      }

    // ---- odd cluster: 16 MFMAs on bB ----
    float4v dO[4];
    __builtin_amdgcn_s_setprio(1);
#pragma unroll
    for (int sub = 0; sub < 4; ++sub)
      dO[sub] = __builtin_amdgcn_mfma_f32_16x16x32_bf16(a[sub][0], bB[0], z4, 0, 0, 0);
#pragma unroll
    for (int ks = 1; ks < 4; ++ks)
#pragma unroll
      for (int sub = 0; sub < 4; ++sub)
        dO[sub] = __builtin_amdgcn_mfma_f32_16x16x32_bf16(a[sub][ks], bB[ks], dO[sub], 0, 0, 0);
    __builtin_amdgcn_s_setprio(0);
    if (g + 3 < g1) {                            // refill bB while MFMAs run
#pragma unroll
      for (int ks = 0; ks < 4; ++ks)
        bB[ks] = *(const short8v*)(keys_fr + (((g + 3) * 4 + ks) * 64 + lane) * 8);
    }
    float vvB = vB;
    if (g + 3 < g1) vB = vpad[(g + 3) * 16 + ln];

    // ---- VALU part B: finish odd group ----
#pragma unroll
    for (int sub = 0; sub < 4; ++sub)
#pragma unroll
      for (int r2 = 0; r2 < 4; ++r2) {
        float pO = EXP2F(dO[sub][r2]);
        lsum[sub][r2] += pO;
        asum[sub][r2] = fmaf(pO, vvB, asum[sub][r2]);
      }
  }

  // reduce over the 16 key-column lanes (same quad); lane ln==0 writes
#pragma unroll
  for (int sub = 0; sub < 4; ++sub)
#pragma unroll
    for (int r2 = 0; r2 < 4; ++r2) {
      float L = lsum[sub][r2], A = asum[sub][r2];
#pragma unroll
      for (int m = 1; m < 16; m <<= 1) {
        L += __shfl_xor(L, m, 64);
        A += __shfl_xor(A, m, 64);
      }
      if (ln == 0) {
        int q = qbase + sub * 16 + quad * 4 + r2;
        partials[(q * NSLICES_ + slice) * 2 + 0] = L;
        partials[(q * NSLICES_ + slice) * 2 + 1] = A;
      }
    }
}

// ---------------------------------------------------------------------------
// Kernel 2: combine slice partials, subtract exact pad-key lsum bias, mean
// over heads, add curiosity.
// ---------------------------------------------------------------------------
__global__ __launch_bounds__(256) void finalize_kernel(
    const float* __restrict__ partials, const float* __restrict__ cur,
    float* __restrict__ out) {
  int tid = blockIdx.x * 256 + threadIdx.x;      // 4096 threads
  int bt = tid >> 3, h = tid & 7;
  int q = bt * NHEADS + h;
  const float4* p = (const float4*)(partials + q * NSLICES_ * 2);
  float sl = 0.f, sa = 0.f;
#pragma unroll
  for (int i = 0; i < NSLICES_ / 2; ++i) {       // 2 slices per float4
    float4 v = p[i];
    sl += v.x + v.z;
    sa += v.y + v.w;
  }
  sl -= NPADKEYS_;                               // exact: pad keys give p=1,v=0
  float r = sa / sl;
  r += __shfl_xor(r, 1, 64);
  r += __shfl_xor(r, 2, 64);
  r += __shfl_xor(r, 4, 64);
  if (h == 0) out[bt] = r * (1.f / NHEADS) + cur[bt];
}

// ---------------------------------------------------------------------------
extern "C" void kernel_launch(void* const* d_in, const int* in_sizes, int n_in,
                              void* d_out, int out_size, void* d_ws, size_t ws_size,
                              hipStream_t stream) {
  (void)in_sizes; (void)n_in; (void)out_size; (void)ws_size;
  const float* x      = (const float*)d_in[0];   // (4,128,1024)
  const float* cur    = (const float*)d_in[1];   // (4,128)
  const float* Wq     = (const float*)d_in[2];   // (1024,1024)
  const float* keys   = (const float*)d_in[3];   // (50000,128)
  const float* values = (const float*)d_in[4];   // (50000,)
  float* out = (float*)d_out;                    // (4,128,1) fp32

  // workspace layout (16B-aligned), ~15.7 MiB total
  char* ws = (char*)d_ws;
  short* keys_fr = (short*)(ws);                        // 13,107,200 B (3200 grp)
  float* vpad    = (float*)(ws + 13107200);             //    204,800 B
  short* qb      = (short*)(ws + 13312000);             //  1,048,576 B
  float* part    = (float*)(ws + 14360576);             //  2,097,152 B (64 slices)

  hipLaunchKernelGGL(prep_kernel, dim3(PROJB_ + CONVB_), dim3(256), 0, stream,
                     x, Wq, qb, keys, values, keys_fr, vpad);
  hipLaunchKernelGGL(attn_kernel, dim3(1024), dim3(256), 0, stream,
                     qb, keys_fr, vpad, part);
  hipLaunchKernelGGL(finalize_kernel, dim3(16), dim3(256), 0, stream, part, cur, out);
}